// Round 4
// baseline (53.742 us; speedup 1.0000x reference)
//
#include <hip/hip_runtime.h>

// Kronecker product: out[i*64+p, j*64+q] = A[i,j] * B[p,q]
// A: 128x128 f32, B: 64x64 f32, out: 8192x8192 f32 (256 MB) -> write-BW bound.
//
// One 256-thread block per output row (2048 float4). Each thread: 8 float4
// stores at wave-stride (each store = coalesced 1 KB wave-write), ONE B load
// (b4 invariant across the 8 stores: q depends only on lane&15), 8 independent
// A loads hoisted up front. Goal: amortize wave lifecycle + load latency over
// 8 KB of stores per wave instead of 1 KB.

constexpr int Ac = 128;
constexpr int Bc = 64;

typedef float f32x4 __attribute__((ext_vector_type(4)));

__global__ __launch_bounds__(256) void kron_kernel(
    const float* __restrict__ A,
    const float* __restrict__ B,
    float* __restrict__ out)
{
    const int r    = blockIdx.x;        // output row, 0..8191
    const int tid  = threadIdx.x;
    const int wave = tid >> 6;          // 0..3
    const int lane = tid & 63;

    const int i = r >> 6;               // A row
    const int p = r & 63;               // B row

    // b4: column q = 4*(lane&15) — same for all 8 stores of this thread.
    const f32x4 b4 = *reinterpret_cast<const f32x4*>(&B[p * Bc + ((lane & 15) << 2)]);

    // store k (k=0..7): float4 col index c4 = wave*512 + k*64 + lane
    //   -> A col j = c4 >> 4 = wave*32 + k*4 + (lane>>4)
    const int abase = i * Ac + (wave << 5) + (lane >> 4);
    float a[8];
#pragma unroll
    for (int k = 0; k < 8; ++k)
        a[k] = A[abase + (k << 2)];     // 8 independent L1-hit loads

    f32x4* __restrict__ o4 = reinterpret_cast<f32x4*>(out) + r * 2048 + (wave << 9) + lane;
#pragma unroll
    for (int k = 0; k < 8; ++k) {
        const f32x4 o = a[k] * b4;
        __builtin_nontemporal_store(o, o4 + (k << 6));  // stride 64 float4 = 1 KB/wave, coalesced
    }
}

extern "C" void kernel_launch(void* const* d_in, const int* in_sizes, int n_in,
                              void* d_out, int out_size, void* d_ws, size_t ws_size,
                              hipStream_t stream)
{
    const float* A = (const float*)d_in[0];
    const float* B = (const float*)d_in[1];
    float* out = (float*)d_out;

    // 8192 rows -> 8192 blocks x 256 threads; each block writes one 32 KB row.
    kron_kernel<<<8192, 256, 0, stream>>>(A, B, out);
}

// Round 5
// 45.958 us; speedup vs baseline: 1.1694x; 1.1694x over previous
//
#include <hip/hip_runtime.h>

// Kronecker product: out[i*64+p, j*64+q] = A[i,j] * B[p,q]
// A: 128x128 f32, B: 64x64 f32, out: 8192x8192 f32 (256 MB) -> write-BW bound.
//
// Measured-best structure (R0/R1: 45.8 us ~= 5.9 TB/s effective, ~6.2 TB/s
// in-kernel). Grid-stride, one float4 store per iteration, A/B reads are
// L1/L2-hits. nt-store (R3) neutral; 8-store batching (R4) regressed.
// Floor: 268 MB / 6.3 TB/s achievable = 42.6 us + launch/ramp.

constexpr int Ac = 128;
constexpr int Bc = 64;
// out has 8192 columns = 2048 float4 per row.

__global__ __launch_bounds__(256) void kron_kernel(
    const float* __restrict__ A,
    const float* __restrict__ B,
    float* __restrict__ out,
    int total4)
{
    const int stride = gridDim.x * blockDim.x;
    for (int idx = blockIdx.x * blockDim.x + threadIdx.x; idx < total4; idx += stride) {
        const int r  = idx >> 11;      // output row (2048 float4 per row)
        const int c4 = idx & 2047;     // float4 index within row
        const int c  = c4 << 2;        // float column
        const int i  = r >> 6;         // A row
        const int p  = r & 63;         // B row
        const int j  = c >> 6;         // A col (constant across the float4: Bc=64, 4-aligned)
        const int q  = c & 63;         // B col

        const float  a  = A[i * Ac + j];
        const float4 b4 = *reinterpret_cast<const float4*>(&B[p * Bc + q]);

        float4 o;
        o.x = a * b4.x;
        o.y = a * b4.y;
        o.z = a * b4.z;
        o.w = a * b4.w;
        reinterpret_cast<float4*>(out)[idx] = o;
    }
}

extern "C" void kernel_launch(void* const* d_in, const int* in_sizes, int n_in,
                              void* d_out, int out_size, void* d_ws, size_t ws_size,
                              hipStream_t stream)
{
    const float* A = (const float*)d_in[0];
    const float* B = (const float*)d_in[1];
    float* out = (float*)d_out;

    const int total4 = out_size / 4;          // 16,777,216 float4 stores
    const int block = 256;
    const int grid = 2048;                    // 256 CUs x 8 blocks, grid-stride

    kron_kernel<<<grid, block, 0, stream>>>(A, B, out, total4);
}